// Round 7
// baseline (260.184 us; speedup 1.0000x reference)
//
#include <hip/hip_runtime.h>

#define EMB 2048
#define UDIM 256
#define KTOT 2304
#define NE 64
#define TOPK 8
#define SSH 6144              // shorts per k-step in wb (12288 B)
#define STEPB 12288           // bytes per k-step
#define KSPL 12               // K-split factor
#define SPS 6                 // k-steps per slice (72/12)
#define SLICEB (SPS * STEPB)  // 73728 B LDS slice -> 2 blocks/CU
#define NB 64                 // tile-group blocks per slice
#define NTOK 16384
#define PART_OFF (1 << 20)    // partial buffer offset in workspace (bytes)

typedef __attribute__((ext_vector_type(8))) short short8;
typedef __attribute__((ext_vector_type(4))) float f32x4;
typedef __attribute__((ext_vector_type(4))) unsigned int u32x4;

__device__ __forceinline__ unsigned short bf16h(float x) {
  unsigned uu = __builtin_bit_cast(unsigned, x);
  return (unsigned short)((uu + 0x7FFFu + ((uu >> 16) & 1u)) >> 16);
}
__device__ __forceinline__ float bf2f(unsigned short s) {
  return __builtin_bit_cast(float, ((unsigned)s) << 16);
}

// packed RNE f32x2 -> bf16x2
__device__ __forceinline__ unsigned cvtpk(float a, float b) {
  unsigned r;
  asm("v_cvt_pk_bf16_f32 %0, %1, %2" : "=v"(r) : "v"(a), "v"(b));
  return r;
}

// ---- prep: W fp32 [2304][64] -> triple-split bf16 in MFMA-FRAGMENT order ----
// wb[kstep][plane][nt][lane][j]:  lane = (kk>>3)*16 + (n&15), j = kk&7
__global__ __launch_bounds__(256)
void prep_w(const float* __restrict__ W, unsigned short* __restrict__ wb) {
  const int flat = blockIdx.x * 256 + threadIdx.x;  // 0..147455
  const int k = flat >> 6;
  const int n = flat & 63;
  const float w = W[flat];
  const unsigned short h0 = bf16h(w);
  const float r1 = w - bf2f(h0);   // exact in fp32
  const unsigned short h1 = bf16h(r1);
  const float r2 = r1 - bf2f(h1);  // exact in fp32
  const unsigned short h2 = bf16h(r2);

  const int s = k >> 5;
  const int kk = k & 31;
  const int lane = (kk >> 3) * 16 + (n & 15);
  const int j = kk & 7;
  const int nt = n >> 4;
  const size_t base = (size_t)s * SSH + ((size_t)nt * 64 + lane) * 8 + j;
  wb[base] = h0;
  wb[base + 2048] = h1;
  wb[base + 4096] = h2;
}

// ---- split-K GEMM: B-stationary in LDS, 4 waves/SIMD, barrier-free loop ----
// Grid = 12 K-slices x 64 blocks. Block stages its 72 KB wb-slice to LDS
// once (2 blocks/CU resident -> staging overlaps the other block's compute);
// 8 waves each compute 2 independent 16-token tiles over 192 k. A is a
// 12-load burst pinned above the step loop by sched_barrier (rule #18);
// one A-buffer live at a time keeps VGPR ~110 under the 128 cap of (512,4).
__global__ __launch_bounds__(512, 4)
void gate_split(const float* __restrict__ h, const float* __restrict__ u,
                const unsigned short* __restrict__ wb,
                float* __restrict__ partial) {
  __shared__ __align__(1024) char lds[SLICEB];  // 72 KB

  const int tid = threadIdx.x;
  const int lane = tid & 63;
  const int wid = __builtin_amdgcn_readfirstlane(tid >> 6);  // 0..7
  const int kq = blockIdx.x >> 6;   // K slice 0..11
  const int bb = blockIdx.x & 63;   // tile-group
  const int mm = lane & 15;         // A: token-in-tile | B: expert%16
  const int q8 = (lane >> 4) * 8;   // k-subgroup within frag

  // ---- stage wb slice (identity byte-map; LDS dest wave-uniform) ----
  const char* src = (const char*)wb + (size_t)kq * SLICEB + (size_t)lane * 16;
  for (int j = wid; j < SPS * 12; j += 8)  // 72 chunks of 1024 B
    __builtin_amdgcn_global_load_lds(
        (const __attribute__((address_space(1))) unsigned int*)(src + (size_t)j * 1024),
        (__attribute__((address_space(3))) unsigned int*)(lds + (size_t)j * 1024),
        16, 0, 0);
  __syncthreads();  // one-time drain; main loop below has no barriers

  const char* lb = lds + (size_t)lane * 16;
  const int ks0 = kq * SPS;  // absolute k-step base of this slice

#pragma unroll 1
  for (int tt = 0; tt < 2; ++tt) {
    const int tile = (bb * 8 + wid) * 2 + tt;
    const int token = tile * 16 + mm;
    const float* hrow = h + (size_t)token * EMB + q8;
    const float* urow = u + (size_t)token * UDIM + q8;

    // burst-load the tile's A slice: 12 dwordx4, wave-uniform h/u select
    f32x4 A[2 * SPS];
#pragma unroll
    for (int s = 0; s < SPS; ++s) {
      const int as = ks0 + s;  // absolute k-step; <64 = h, >=64 = u
      const float* bs = (as < 64) ? (hrow + as * 32) : (urow + (as - 64) * 32);
      A[2 * s] = *(const f32x4*)bs;
      A[2 * s + 1] = *(const f32x4*)(bs + 4);
    }
    __builtin_amdgcn_sched_barrier(0);  // pin the burst above the steps

    f32x4 acc[4];
#pragma unroll
    for (int nt = 0; nt < 4; ++nt) acc[nt] = 0.f;

#pragma unroll
    for (int s = 0; s < SPS; ++s) {
      short8 Bv[12];
#pragma unroll
      for (int q = 0; q < 12; ++q)
        Bv[q] = *(const short8*)(lb + (size_t)s * STEPB + q * 1024);

      const f32x4 c0 = A[2 * s], c1 = A[2 * s + 1];
      const float xs[8] = {c0[0], c0[1], c0[2], c0[3],
                           c1[0], c1[1], c1[2], c1[3]};
      u32x4 W0, W1, W2;
#pragma unroll
      for (int k2 = 0; k2 < 4; ++k2) {
        const float a = xs[2 * k2], bbv = xs[2 * k2 + 1];
        const unsigned p0 = cvtpk(a, bbv);
        const float a1 = a - __builtin_bit_cast(float, p0 << 16);
        const float b1 = bbv - __builtin_bit_cast(float, p0 & 0xFFFF0000u);
        const unsigned p1 = cvtpk(a1, b1);
        const float a2 = a1 - __builtin_bit_cast(float, p1 << 16);
        const float b2 = b1 - __builtin_bit_cast(float, p1 & 0xFFFF0000u);
        const unsigned p2 = cvtpk(a2, b2);
        W0[k2] = p0; W1[k2] = p1; W2[k2] = p2;
      }
      const short8 A0 = __builtin_bit_cast(short8, W0);
      const short8 A1 = __builtin_bit_cast(short8, W1);
      const short8 A2 = __builtin_bit_cast(short8, W2);

#pragma unroll
      for (int nt = 0; nt < 4; ++nt) {
        acc[nt] = __builtin_amdgcn_mfma_f32_16x16x32_bf16(A0, Bv[0 + nt], acc[nt], 0, 0, 0);
        acc[nt] = __builtin_amdgcn_mfma_f32_16x16x32_bf16(A0, Bv[4 + nt], acc[nt], 0, 0, 0);
        acc[nt] = __builtin_amdgcn_mfma_f32_16x16x32_bf16(A1, Bv[0 + nt], acc[nt], 0, 0, 0);
        acc[nt] = __builtin_amdgcn_mfma_f32_16x16x32_bf16(A1, Bv[4 + nt], acc[nt], 0, 0, 0);
        acc[nt] = __builtin_amdgcn_mfma_f32_16x16x32_bf16(A0, Bv[8 + nt], acc[nt], 0, 0, 0);
        acc[nt] = __builtin_amdgcn_mfma_f32_16x16x32_bf16(A2, Bv[0 + nt], acc[nt], 0, 0, 0);
      }
    }

    // ---- write partial tile: D row(token)=(lane>>4)*4+r, col=nt*16+mm ----
    const int rowb = (lane >> 4) * 4;
#pragma unroll
    for (int nt = 0; nt < 4; ++nt)
#pragma unroll
      for (int r = 0; r < 4; ++r)
        partial[((size_t)kq * NTOK + tile * 16 + rowb + r) * NE + nt * 16 + mm] =
            acc[nt][r];
  }
}

// ---- finalize: reduce 12 partials + bias + softmax + top-8, 1 token/wave ----
__global__ __launch_bounds__(256)
void finalize(const float* __restrict__ partial, const float* __restrict__ b,
              float* __restrict__ out) {
  const int tid = threadIdx.x;
  const int lane = tid & 63;
  const int wv = tid >> 6;  // 0..3
  const int t = blockIdx.x * 4 + wv;  // token
  const float bias = b[lane];

  float g = bias;
#pragma unroll
  for (int s = 0; s < KSPL; ++s)
    g += partial[((size_t)s * NTOK + t) * NE + lane];

  float m = g;
#pragma unroll
  for (int off = 32; off > 0; off >>= 1)
    m = fmaxf(m, __shfl_xor(m, off));
  float pexp = __expf(g - m);
  float sum = pexp;
#pragma unroll
  for (int off = 32; off > 0; off >>= 1)
    sum += __shfl_xor(sum, off);
  const float pn = pexp / sum;

  float vv = pn;
  float topsum = 0.f;
  int sel = 0;
  for (int r = 0; r < TOPK; ++r) {
    float mv = vv;
    int mi = lane;
#pragma unroll
    for (int off = 32; off > 0; off >>= 1) {
      const float ov = __shfl_xor(mv, off);
      const int oi = __shfl_xor(mi, off);
      if (ov > mv || (ov == mv && oi < mi)) { mv = ov; mi = oi; }
    }
    topsum += mv;
    if (lane == mi) { sel = 1; vv = -1.f; }
  }

  out[(size_t)t * NE + lane] = sel ? pn / (topsum + 1e-9f) : 0.f;
}

extern "C" void kernel_launch(void* const* d_in, const int* in_sizes, int n_in,
                              void* d_out, int out_size, void* d_ws, size_t ws_size,
                              hipStream_t stream) {
  const float* h = (const float*)d_in[0];
  const float* u = (const float*)d_in[1];
  const float* W = (const float*)d_in[2];
  const float* b = (const float*)d_in[3];
  float* out = (float*)d_out;

  unsigned short* wb = (unsigned short*)d_ws;           // 884736 B
  float* partial = (float*)((char*)d_ws + PART_OFF);    // 12*16384*64*4 = 50.3 MB

  hipLaunchKernelGGL(prep_w, dim3(KTOT * NE / 256), dim3(256), 0, stream, W, wb);
  hipLaunchKernelGGL(gate_split, dim3(KSPL * NB), dim3(512), 0, stream,
                     h, u, wb, partial);
  hipLaunchKernelGGL(finalize, dim3(NTOK / 4), dim3(256), 0, stream,
                     partial, b, out);
}

// Round 8
// 258.613 us; speedup vs baseline: 1.0061x; 1.0061x over previous
//
#include <hip/hip_runtime.h>

#define EMB 2048
#define UDIM 256
#define KTOT 2304
#define NE 64
#define TOPK 8
#define SSH 6144              // shorts per k-step in wb (12288 B)
#define STEPB 12288           // bytes per k-step
#define KSPL 12               // K-split factor
#define SPS 6                 // k-steps per slice (72/12)
#define SLICEB (SPS * STEPB)  // 73728 B LDS slice -> 2 blocks/CU
#define NB 64                 // tile-group blocks per slice
#define NTOK 16384
#define PART_OFF (1 << 20)    // partial buffer offset in workspace (bytes)

typedef __attribute__((ext_vector_type(8))) short short8;
typedef __attribute__((ext_vector_type(4))) float f32x4;
typedef __attribute__((ext_vector_type(4))) unsigned int u32x4;

__device__ __forceinline__ unsigned short bf16h(float x) {
  unsigned uu = __builtin_bit_cast(unsigned, x);
  return (unsigned short)((uu + 0x7FFFu + ((uu >> 16) & 1u)) >> 16);
}
__device__ __forceinline__ float bf2f(unsigned short s) {
  return __builtin_bit_cast(float, ((unsigned)s) << 16);
}

// packed RNE f32x2 -> bf16x2
__device__ __forceinline__ unsigned cvtpk(float a, float b) {
  unsigned r;
  asm("v_cvt_pk_bf16_f32 %0, %1, %2" : "=v"(r) : "v"(a), "v"(b));
  return r;
}

// un-sinkable global load: asm volatile output regs MUST stay live.
// "memory" clobber pins program order vs compiler stores -> deterministic
// vmcnt counts. NOT tracked by SIInsertWaitcnts: we wait manually.
__device__ __forceinline__ f32x4 gld(const float* p) {
  f32x4 r;
  asm volatile("global_load_dwordx4 %0, %1, off" : "=v"(r) : "v"(p) : "memory");
  return r;
}

// ---- prep: W fp32 [2304][64] -> triple-split bf16 in MFMA-FRAGMENT order ----
// wb[kstep][plane][nt][lane][j]:  lane = (kk>>3)*16 + (n&15), j = kk&7
__global__ __launch_bounds__(256)
void prep_w(const float* __restrict__ W, unsigned short* __restrict__ wb) {
  const int flat = blockIdx.x * 256 + threadIdx.x;  // 0..147455
  const int k = flat >> 6;
  const int n = flat & 63;
  const float w = W[flat];
  const unsigned short h0 = bf16h(w);
  const float r1 = w - bf2f(h0);   // exact in fp32
  const unsigned short h1 = bf16h(r1);
  const float r2 = r1 - bf2f(h1);  // exact in fp32
  const unsigned short h2 = bf16h(r2);

  const int s = k >> 5;
  const int kk = k & 31;
  const int lane = (kk >> 3) * 16 + (n & 15);
  const int j = kk & 7;
  const int nt = n >> 4;
  const size_t base = (size_t)s * SSH + ((size_t)nt * 64 + lane) * 8 + j;
  wb[base] = h0;
  wb[base + 2048] = h1;
  wb[base + 4096] = h2;
}

// per-step math: triple-split convert of 8 fp32 A values + 24 MFMAs
__device__ __forceinline__ void step_math(const f32x4& c0, const f32x4& c1,
                                          const short8* Bv, f32x4* acc) {
  const float xs[8] = {c0[0], c0[1], c0[2], c0[3],
                       c1[0], c1[1], c1[2], c1[3]};
  u32x4 W0, W1, W2;
#pragma unroll
  for (int k2 = 0; k2 < 4; ++k2) {
    const float a = xs[2 * k2], bbv = xs[2 * k2 + 1];
    const unsigned p0 = cvtpk(a, bbv);
    const float a1 = a - __builtin_bit_cast(float, p0 << 16);
    const float b1 = bbv - __builtin_bit_cast(float, p0 & 0xFFFF0000u);
    const unsigned p1 = cvtpk(a1, b1);
    const float a2 = a1 - __builtin_bit_cast(float, p1 << 16);
    const float b2 = b1 - __builtin_bit_cast(float, p1 & 0xFFFF0000u);
    const unsigned p2 = cvtpk(a2, b2);
    W0[k2] = p0; W1[k2] = p1; W2[k2] = p2;
  }
  const short8 A0 = __builtin_bit_cast(short8, W0);
  const short8 A1 = __builtin_bit_cast(short8, W1);
  const short8 A2 = __builtin_bit_cast(short8, W2);

#pragma unroll
  for (int nt = 0; nt < 4; ++nt) {
    acc[nt] = __builtin_amdgcn_mfma_f32_16x16x32_bf16(A0, Bv[0 + nt], acc[nt], 0, 0, 0);
    acc[nt] = __builtin_amdgcn_mfma_f32_16x16x32_bf16(A0, Bv[4 + nt], acc[nt], 0, 0, 0);
    acc[nt] = __builtin_amdgcn_mfma_f32_16x16x32_bf16(A1, Bv[0 + nt], acc[nt], 0, 0, 0);
    acc[nt] = __builtin_amdgcn_mfma_f32_16x16x32_bf16(A1, Bv[4 + nt], acc[nt], 0, 0, 0);
    acc[nt] = __builtin_amdgcn_mfma_f32_16x16x32_bf16(A0, Bv[8 + nt], acc[nt], 0, 0, 0);
    acc[nt] = __builtin_amdgcn_mfma_f32_16x16x32_bf16(A2, Bv[0 + nt], acc[nt], 0, 0, 0);
  }
}

// step S: counted wait (10-2S) threaded through the two A-regs ("+v" creates
// the data dep that orders consumers after the wait, rule #18), then B
// ds_reads (lgkm, compiler-managed) + math.
#define STEP(S, NW, alo, ahi)                                              \
  do {                                                                     \
    asm volatile("s_waitcnt vmcnt(" #NW ")" : "+v"(alo), "+v"(ahi));       \
    short8 Bv[12];                                                         \
    _Pragma("unroll")                                                      \
    for (int q = 0; q < 12; ++q)                                           \
      Bv[q] = *(const short8*)(lb + (S) * STEPB + q * 1024);               \
    step_math(alo, ahi, Bv, acc);                                          \
  } while (0)

// ---- split-K GEMM: B-stationary in LDS, asm-pinned A burst ----
// Grid = 12 K-slices x 64 blocks, 2 blocks/CU. 8 waves x 2 tiles each.
// Per tile: 12 asm global_load_dwordx4 issued up front (un-sinkable),
// 6 steps consume them with vmcnt(10/8/6/4/2/0) -> first MFMA fires after
// 2 loads land; steady state never drains.
__global__ __launch_bounds__(512, 4)
void gate_split(const float* __restrict__ h, const float* __restrict__ u,
                const unsigned short* __restrict__ wb,
                float* __restrict__ partial) {
  __shared__ __align__(1024) char lds[SLICEB];  // 72 KB

  const int tid = threadIdx.x;
  const int lane = tid & 63;
  const int wid = __builtin_amdgcn_readfirstlane(tid >> 6);  // 0..7
  const int kq = blockIdx.x >> 6;   // K slice 0..11
  const int bb = blockIdx.x & 63;   // tile-group
  const int mm = lane & 15;         // A: token-in-tile | B: expert%16
  const int q8 = (lane >> 4) * 8;   // k-subgroup within frag

  // ---- stage wb slice (identity byte-map; LDS dest wave-uniform) ----
  const char* src = (const char*)wb + (size_t)kq * SLICEB + (size_t)lane * 16;
  for (int j = wid; j < SPS * 12; j += 8)  // 72 chunks of 1024 B
    __builtin_amdgcn_global_load_lds(
        (const __attribute__((address_space(1))) unsigned int*)(src + (size_t)j * 1024),
        (__attribute__((address_space(3))) unsigned int*)(lds + (size_t)j * 1024),
        16, 0, 0);
  __syncthreads();  // one-time drain; main loop below has no barriers

  const char* lb = lds + (size_t)lane * 16;
  const int ks0 = kq * SPS;  // absolute k-step base of this slice

#pragma unroll 1
  for (int tt = 0; tt < 2; ++tt) {
    const int tile = (bb * 8 + wid) * 2 + tt;
    const int token = tile * 16 + mm;
    const float* hrow = h + (size_t)token * EMB + q8;
    const float* urow = u + (size_t)token * UDIM + q8;

    // issue the tile's full A burst: 12 un-sinkable loads, in step order
    f32x4 a0l, a0h, a1l, a1h, a2l, a2h, a3l, a3h, a4l, a4h, a5l, a5h;
#define AISSUE(S, vlo, vhi)                                                \
    {                                                                      \
      const int as = ks0 + (S);                                            \
      const float* ps = (as < 64) ? (hrow + as * 32)                       \
                                  : (urow + (as - 64) * 32);               \
      vlo = gld(ps);                                                       \
      vhi = gld(ps + 4);                                                   \
    }
    AISSUE(0, a0l, a0h)
    AISSUE(1, a1l, a1h)
    AISSUE(2, a2l, a2h)
    AISSUE(3, a3l, a3h)
    AISSUE(4, a4l, a4h)
    AISSUE(5, a5l, a5h)
#undef AISSUE

    f32x4 acc[4];
#pragma unroll
    for (int nt = 0; nt < 4; ++nt) acc[nt] = 0.f;

    STEP(0, 10, a0l, a0h);
    STEP(1, 8, a1l, a1h);
    STEP(2, 6, a2l, a2h);
    STEP(3, 4, a3l, a3h);
    STEP(4, 2, a4l, a4h);
    STEP(5, 0, a5l, a5h);

    // ---- write partial tile: D row(token)=(lane>>4)*4+r, col=nt*16+mm ----
    const int rowb = (lane >> 4) * 4;
#pragma unroll
    for (int nt = 0; nt < 4; ++nt)
#pragma unroll
      for (int r = 0; r < 4; ++r)
        partial[((size_t)kq * NTOK + tile * 16 + rowb + r) * NE + nt * 16 + mm] =
            acc[nt][r];
  }
}

// ---- finalize: reduce 12 partials + bias + softmax + top-8, 1 token/wave ----
__global__ __launch_bounds__(256)
void finalize(const float* __restrict__ partial, const float* __restrict__ b,
              float* __restrict__ out) {
  const int tid = threadIdx.x;
  const int lane = tid & 63;
  const int wv = tid >> 6;  // 0..3
  const int t = blockIdx.x * 4 + wv;  // token
  const float bias = b[lane];

  float g = bias;
#pragma unroll
  for (int s = 0; s < KSPL; ++s)
    g += partial[((size_t)s * NTOK + t) * NE + lane];

  float m = g;
#pragma unroll
  for (int off = 32; off > 0; off >>= 1)
    m = fmaxf(m, __shfl_xor(m, off));
  float pexp = __expf(g - m);
  float sum = pexp;
#pragma unroll
  for (int off = 32; off > 0; off >>= 1)
    sum += __shfl_xor(sum, off);
  const float pn = pexp / sum;

  float vv = pn;
  float topsum = 0.f;
  int sel = 0;
  for (int r = 0; r < TOPK; ++r) {
    float mv = vv;
    int mi = lane;
#pragma unroll
    for (int off = 32; off > 0; off >>= 1) {
      const float ov = __shfl_xor(mv, off);
      const int oi = __shfl_xor(mi, off);
      if (ov > mv || (ov == mv && oi < mi)) { mv = ov; mi = oi; }
    }
    topsum += mv;
    if (lane == mi) { sel = 1; vv = -1.f; }
  }

  out[(size_t)t * NE + lane] = sel ? pn / (topsum + 1e-9f) : 0.f;
}

extern "C" void kernel_launch(void* const* d_in, const int* in_sizes, int n_in,
                              void* d_out, int out_size, void* d_ws, size_t ws_size,
                              hipStream_t stream) {
  const float* h = (const float*)d_in[0];
  const float* u = (const float*)d_in[1];
  const float* W = (const float*)d_in[2];
  const float* b = (const float*)d_in[3];
  float* out = (float*)d_out;

  unsigned short* wb = (unsigned short*)d_ws;           // 884736 B
  float* partial = (float*)((char*)d_ws + PART_OFF);    // 12*16384*64*4 = 50.3 MB

  hipLaunchKernelGGL(prep_w, dim3(KTOT * NE / 256), dim3(256), 0, stream, W, wb);
  hipLaunchKernelGGL(gate_split, dim3(KSPL * NB), dim3(512), 0, stream,
                     h, u, wb, partial);
  hipLaunchKernelGGL(finalize, dim3(NTOK / 4), dim3(256), 0, stream,
                     partial, b, out);
}

// Round 9
// 241.509 us; speedup vs baseline: 1.0773x; 1.0708x over previous
//
#include <hip/hip_runtime.h>

#define EMB 2048
#define UDIM 256
#define KTOT 2304
#define NE 64
#define TOPK 8
#define SSH 6144              // shorts per k-step in wb (12288 B)
#define STEPB 12288           // bytes per k-step
#define KSPL 8                // K-split factor (measured-best: dur 243)
#define SPS 9                 // k-steps per slice (72/8)
#define SLICEB (SPS * STEPB)  // 110592 B LDS slice
#define NTOK 16384
#define PART_OFF (1 << 20)    // partial buffer offset in workspace (bytes)

typedef __attribute__((ext_vector_type(8))) short short8;
typedef __attribute__((ext_vector_type(4))) float f32x4;
typedef __attribute__((ext_vector_type(4))) unsigned int u32x4;

__device__ __forceinline__ unsigned short bf16h(float x) {
  unsigned uu = __builtin_bit_cast(unsigned, x);
  return (unsigned short)((uu + 0x7FFFu + ((uu >> 16) & 1u)) >> 16);
}
__device__ __forceinline__ float bf2f(unsigned short s) {
  return __builtin_bit_cast(float, ((unsigned)s) << 16);
}

// packed RNE f32x2 -> bf16x2
__device__ __forceinline__ unsigned cvtpk(float a, float b) {
  unsigned r;
  asm("v_cvt_pk_bf16_f32 %0, %1, %2" : "=v"(r) : "v"(a), "v"(b));
  return r;
}

// un-sinkable global load (asm volatile output must stay live; "memory"
// clobber pins issue order vs compiler stores -> deterministic vmcnt).
__device__ __forceinline__ f32x4 gld(const float* p) {
  f32x4 r;
  asm volatile("global_load_dwordx4 %0, %1, off" : "=v"(r) : "v"(p) : "memory");
  return r;
}

// ---- prep: W fp32 [2304][64] -> triple-split bf16 in MFMA-FRAGMENT order ----
// wb[kstep][plane][nt][lane][j]:  lane = (kk>>3)*16 + (n&15), j = kk&7
__global__ __launch_bounds__(256)
void prep_w(const float* __restrict__ W, unsigned short* __restrict__ wb) {
  const int flat = blockIdx.x * 256 + threadIdx.x;  // 0..147455
  const int k = flat >> 6;
  const int n = flat & 63;
  const float w = W[flat];
  const unsigned short h0 = bf16h(w);
  const float r1 = w - bf2f(h0);   // exact in fp32
  const unsigned short h1 = bf16h(r1);
  const float r2 = r1 - bf2f(h1);  // exact in fp32
  const unsigned short h2 = bf16h(r2);

  const int s = k >> 5;
  const int kk = k & 31;
  const int lane = (kk >> 3) * 16 + (n & 15);
  const int j = kk & 7;
  const int nt = n >> 4;
  const size_t base = (size_t)s * SSH + ((size_t)nt * 64 + lane) * 8 + j;
  wb[base] = h0;
  wb[base + 2048] = h1;
  wb[base + 4096] = h2;
}

// per-step math: triple-split convert of 8 fp32 A values + 24 MFMAs
__device__ __forceinline__ void step_math(const f32x4& c0, const f32x4& c1,
                                          const short8* Bv, f32x4* acc) {
  const float xs[8] = {c0[0], c0[1], c0[2], c0[3],
                       c1[0], c1[1], c1[2], c1[3]};
  u32x4 W0, W1, W2;
#pragma unroll
  for (int k2 = 0; k2 < 4; ++k2) {
    const float a = xs[2 * k2], bbv = xs[2 * k2 + 1];
    const unsigned p0 = cvtpk(a, bbv);
    const float a1 = a - __builtin_bit_cast(float, p0 << 16);
    const float b1 = bbv - __builtin_bit_cast(float, p0 & 0xFFFF0000u);
    const unsigned p1 = cvtpk(a1, b1);
    const float a2 = a1 - __builtin_bit_cast(float, p1 << 16);
    const float b2 = b1 - __builtin_bit_cast(float, p1 & 0xFFFF0000u);
    const unsigned p2 = cvtpk(a2, b2);
    W0[k2] = p0; W1[k2] = p1; W2[k2] = p2;
  }
  const short8 A0 = __builtin_bit_cast(short8, W0);
  const short8 A1 = __builtin_bit_cast(short8, W1);
  const short8 A2 = __builtin_bit_cast(short8, W2);

#pragma unroll
  for (int nt = 0; nt < 4; ++nt) {
    acc[nt] = __builtin_amdgcn_mfma_f32_16x16x32_bf16(A0, Bv[0 + nt], acc[nt], 0, 0, 0);
    acc[nt] = __builtin_amdgcn_mfma_f32_16x16x32_bf16(A0, Bv[4 + nt], acc[nt], 0, 0, 0);
    acc[nt] = __builtin_amdgcn_mfma_f32_16x16x32_bf16(A1, Bv[0 + nt], acc[nt], 0, 0, 0);
    acc[nt] = __builtin_amdgcn_mfma_f32_16x16x32_bf16(A1, Bv[4 + nt], acc[nt], 0, 0, 0);
    acc[nt] = __builtin_amdgcn_mfma_f32_16x16x32_bf16(A0, Bv[8 + nt], acc[nt], 0, 0, 0);
    acc[nt] = __builtin_amdgcn_mfma_f32_16x16x32_bf16(A2, Bv[0 + nt], acc[nt], 0, 0, 0);
  }
}

// step S with counted wait NW: "+v" on the two A-regs orders consumers
// after the wait (rule #18); B ds_reads are compiler-managed (lgkmcnt).
#define TSTEP(S, NW, Arr)                                                  \
  do {                                                                     \
    asm volatile("s_waitcnt vmcnt(" #NW ")"                                \
                 : "+v"(Arr[2 * (S)]), "+v"(Arr[2 * (S) + 1]));            \
    short8 Bv[12];                                                         \
    _Pragma("unroll")                                                      \
    for (int q = 0; q < 12; ++q)                                           \
      Bv[q] = *(const short8*)(lb + (S) * STEPB + q * 1024);               \
    step_math(Arr[2 * (S)], Arr[2 * (S) + 1], Bv, acc);                    \
  } while (0)

// issue one tile's full A burst: 18 un-sinkable dwordx4 in step order
#define AISSUE(tile_, Arr)                                                 \
  do {                                                                     \
    const int _tok = (tile_) * 16 + mm;                                    \
    const float* _hr = h + (size_t)_tok * EMB + q8;                        \
    const float* _ur = u + (size_t)_tok * UDIM + q8;                       \
    _Pragma("unroll")                                                      \
    for (int s = 0; s < SPS; ++s) {                                        \
      const float* _ps;                                                    \
      if (!tail) _ps = _hr + (ks0 + s) * 32;                               \
      else _ps = (s == 0) ? (_hr + 2016) : (_ur + (s - 1) * 32);           \
      Arr[2 * s] = gld(_ps);                                               \
      Arr[2 * s + 1] = gld(_ps + 4);                                       \
    }                                                                      \
  } while (0)

// ---- split-K GEMM: B-stationary LDS, cross-tile asm A-prefetch ----
// Grid = 8 K-slices x 32 blocks (1 block/CU, LDS 108 KB). 8 waves x 4 tiles.
// A(next) issued mid-tile (~2000 cy cover); per-step counted vmcnt never
// drains (prev tile's 16 stores ride along in the queue).
// Queue math: tile entry [A(cur)18, St(prev)16] -> steps0..4 wait 32-2s;
// after issuing A(next): steps5..8 wait 50-2s. Tile0: 16-2s / 34-2s.
// Last tile: 32-2s / 32-2s.
__global__ __launch_bounds__(512, 1)
void gate_split(const float* __restrict__ h, const float* __restrict__ u,
                const unsigned short* __restrict__ wb,
                float* __restrict__ partial) {
  __shared__ __align__(1024) char lds[SLICEB];  // 108 KB

  const int tid = threadIdx.x;
  const int lane = tid & 63;
  const int wid = __builtin_amdgcn_readfirstlane(tid >> 6);  // 0..7
  const int kq = blockIdx.x >> 5;   // K slice 0..7
  const int bb = blockIdx.x & 31;   // tile-group
  const int mm = lane & 15;         // A: token-in-tile | B: expert%16
  const int q8 = (lane >> 4) * 8;   // k-subgroup within frag

  // ---- stage wb slice (identity byte-map; LDS dest wave-uniform) ----
  const char* src = (const char*)wb + (size_t)kq * SLICEB + (size_t)lane * 16;
  for (int j = wid; j < SPS * 12; j += 8)  // 108 chunks of 1024 B
    __builtin_amdgcn_global_load_lds(
        (const __attribute__((address_space(1))) unsigned int*)(src + (size_t)j * 1024),
        (__attribute__((address_space(3))) unsigned int*)(lds + (size_t)j * 1024),
        16, 0, 0);
  __syncthreads();  // drains vmcnt -> queue empty entering the tile loop

  const bool tail = (kq == KSPL - 1);
  const char* lb = lds + (size_t)lane * 16;
  const int ks0 = kq * SPS;
  const int tb = (bb * 8 + wid) * 4;

  f32x4 acc[4];
#pragma unroll
  for (int nt = 0; nt < 4; ++nt) acc[nt] = 0.f;

  auto store = [&](int tile) {
    const int rowb = (lane >> 4) * 4;
#pragma unroll
    for (int nt = 0; nt < 4; ++nt) {
#pragma unroll
      for (int r = 0; r < 4; ++r)
        partial[((size_t)kq * NTOK + tile * 16 + rowb + r) * NE + nt * 16 + mm] =
            acc[nt][r];
      acc[nt] = 0.f;
    }
  };

  f32x4 Aa[2 * SPS], Ab[2 * SPS];

  // ---- tile 0 ----
  AISSUE(tb + 0, Aa);
  TSTEP(0, 16, Aa); TSTEP(1, 14, Aa); TSTEP(2, 12, Aa);
  TSTEP(3, 10, Aa); TSTEP(4, 8, Aa);
  AISSUE(tb + 1, Ab);
  TSTEP(5, 24, Aa); TSTEP(6, 22, Aa); TSTEP(7, 20, Aa); TSTEP(8, 18, Aa);
  store(tb + 0);

  // ---- tile 1 ----
  TSTEP(0, 32, Ab); TSTEP(1, 30, Ab); TSTEP(2, 28, Ab);
  TSTEP(3, 26, Ab); TSTEP(4, 24, Ab);
  AISSUE(tb + 2, Aa);
  TSTEP(5, 40, Ab); TSTEP(6, 38, Ab); TSTEP(7, 36, Ab); TSTEP(8, 34, Ab);
  store(tb + 1);

  // ---- tile 2 ----
  TSTEP(0, 32, Aa); TSTEP(1, 30, Aa); TSTEP(2, 28, Aa);
  TSTEP(3, 26, Aa); TSTEP(4, 24, Aa);
  AISSUE(tb + 3, Ab);
  TSTEP(5, 40, Aa); TSTEP(6, 38, Aa); TSTEP(7, 36, Aa); TSTEP(8, 34, Aa);
  store(tb + 2);

  // ---- tile 3 (no prefetch) ----
  TSTEP(0, 32, Ab); TSTEP(1, 30, Ab); TSTEP(2, 28, Ab);
  TSTEP(3, 26, Ab); TSTEP(4, 24, Ab);
  TSTEP(5, 22, Ab); TSTEP(6, 20, Ab); TSTEP(7, 18, Ab); TSTEP(8, 16, Ab);
  store(tb + 3);
}

// ---- finalize: reduce 8 partials + bias + softmax + top-8, 1 token/wave ----
__global__ __launch_bounds__(256)
void finalize(const float* __restrict__ partial, const float* __restrict__ b,
              float* __restrict__ out) {
  const int tid = threadIdx.x;
  const int lane = tid & 63;
  const int wv = tid >> 6;  // 0..3
  const int t = blockIdx.x * 4 + wv;  // token
  const float bias = b[lane];

  float g = bias;
#pragma unroll
  for (int s = 0; s < KSPL; ++s)
    g += partial[((size_t)s * NTOK + t) * NE + lane];

  float m = g;
#pragma unroll
  for (int off = 32; off > 0; off >>= 1)
    m = fmaxf(m, __shfl_xor(m, off));
  float pexp = __expf(g - m);
  float sum = pexp;
#pragma unroll
  for (int off = 32; off > 0; off >>= 1)
    sum += __shfl_xor(sum, off);
  const float pn = pexp / sum;

  float vv = pn;
  float topsum = 0.f;
  int sel = 0;
  for (int r = 0; r < TOPK; ++r) {
    float mv = vv;
    int mi = lane;
#pragma unroll
    for (int off = 32; off > 0; off >>= 1) {
      const float ov = __shfl_xor(mv, off);
      const int oi = __shfl_xor(mi, off);
      if (ov > mv || (ov == mv && oi < mi)) { mv = ov; mi = oi; }
    }
    topsum += mv;
    if (lane == mi) { sel = 1; vv = -1.f; }
  }

  out[(size_t)t * NE + lane] = sel ? pn / (topsum + 1e-9f) : 0.f;
}

extern "C" void kernel_launch(void* const* d_in, const int* in_sizes, int n_in,
                              void* d_out, int out_size, void* d_ws, size_t ws_size,
                              hipStream_t stream) {
  const float* h = (const float*)d_in[0];
  const float* u = (const float*)d_in[1];
  const float* W = (const float*)d_in[2];
  const float* b = (const float*)d_in[3];
  float* out = (float*)d_out;

  unsigned short* wb = (unsigned short*)d_ws;           // 884736 B
  float* partial = (float*)((char*)d_ws + PART_OFF);    // 8*16384*64*4 = 33.5 MB

  hipLaunchKernelGGL(prep_w, dim3(KTOT * NE / 256), dim3(256), 0, stream, W, wb);
  hipLaunchKernelGGL(gate_split, dim3(KSPL * 32), dim3(512), 0, stream,
                     h, u, wb, partial);
  hipLaunchKernelGGL(finalize, dim3(NTOK / 4), dim3(256), 0, stream,
                     partial, b, out);
}